// Round 3
// baseline (406.294 us; speedup 1.0000x reference)
//
#include <hip/hip_runtime.h>

#define IN_C   256
#define OUT_C  512
#define WIDTH  56
#define HW     3136        // 56*56
#define KTOT   2304        // IN_C*9
#define NF     64
#define NU     448         // OUT_C - NF
#define NB     32
#define NGRP   8           // ic groups of 32
#define TN     128         // pixels per block
#define NTILE  25          // ceil(3136/128)
#define XROWS  242         // TN + 2*57 halo
#define LDX    40          // padded LDS row stride (bf16 elems) = 80 B

typedef __bf16 bf16x8 __attribute__((ext_vector_type(8)));
typedef float  f32x4  __attribute__((ext_vector_type(4)));

// ---------------- kernel 1: global average pool ----------------
__global__ __launch_bounds__(256) void pool_kernel(const float* __restrict__ x,
                                                   float* __restrict__ pooled) {
    int bc = blockIdx.x;
    const float* src = x + (size_t)bc * HW;
    float s = 0.f;
    for (int i = threadIdx.x; i < HW; i += 256) s += src[i];
    #pragma unroll
    for (int off = 32; off > 0; off >>= 1) s += __shfl_down(s, off, 64);
    __shared__ float wsum[4];
    int lane = threadIdx.x & 63, wv = threadIdx.x >> 6;
    if (lane == 0) wsum[wv] = s;
    __syncthreads();
    if (threadIdx.x == 0)
        pooled[bc] = (wsum[0] + wsum[1] + wsum[2] + wsum[3]) * (1.0f / HW);
}

// ---------------- kernel 2: router GEMV + top-64 selection ----------------
__global__ __launch_bounds__(512) void router_kernel(const float* __restrict__ pooled,
                                                     const float* __restrict__ rw,
                                                     const float* __restrict__ rb,
                                                     int* __restrict__ sel,
                                                     int* __restrict__ unsel) {
    int b = blockIdx.x;
    __shared__ float p[IN_C];
    __shared__ float v[OUT_C];
    __shared__ int   scount, ucount;
    int t = threadIdx.x;
    if (t < IN_C) p[t] = pooled[b * IN_C + t];
    if (t == 0) { scount = 0; ucount = 0; }
    __syncthreads();
    float acc = rb[t];
    const float* wrow = rw + (size_t)t * IN_C;
    for (int i = 0; i < IN_C; ++i) acc += p[i] * wrow[i];
    v[t] = acc;
    __syncthreads();
    // stable rank: count strictly-greater, plus equal-with-lower-index (matches top_k tie rule)
    int cnt = 0;
    for (int j = 0; j < OUT_C; ++j) {
        float o = v[j];
        cnt += (o > acc) || (o == acc && j < t);
    }
    if (cnt < NF) {
        int pos = atomicAdd(&scount, 1);   // order irrelevant: scatter by oc
        sel[b * NF + pos] = t;
    } else {
        int pos = atomicAdd(&ucount, 1);
        unsel[b * NU + pos] = t;
    }
}

// ---------------- kernel 3: weight compaction into MFMA-A fragment layout ----------------
// Acomp[((b*8+g)*9+tap)*64 + oc][32 icl] bf16. blockIdx = b*72 + g*9 + tap.
__global__ __launch_bounds__(256) void compact_w(const float* __restrict__ w,
                                                 const int* __restrict__ sel,
                                                 __bf16* __restrict__ Acomp) {
    int id = blockIdx.x;
    int b = id / 72, rem = id - b * 72;
    int g = rem / 9, tap = rem - g * 9;
    int t = threadIdx.x;
    int oc = t >> 2, q = t & 3;
    int s = sel[b * NF + oc];
    const float* wsrc = w + (size_t)s * KTOT + tap;   // + ic*9
    bf16x8 o;
    #pragma unroll
    for (int j = 0; j < 8; ++j)
        o[j] = (__bf16)wsrc[(g * 32 + q * 8 + j) * 9];
    *(bf16x8*)&Acomp[((size_t)id * 64 + oc) * 32 + q * 8] = o;
}

// ---------------- kernel 4: sparse conv, halo-tile + 9-tap MFMA + fused zero-fill ----------------
// 800 blocks (flattened 25 tiles x 32 batches, XCD-swizzled), 256 threads = 4 waves.
// Block: M=64 selected ocs x N=128 px. Wave: M64 x N32 (4 m-frags x 2 n-frags).
// K-loop: 8 ic-groups of 32; per group one LDS x-slab (242 px x 32 ic) serves 9 taps.
// Epilogue also zero-fills the 448 unselected planes for this block's px range.
__global__ __launch_bounds__(256, 4) void conv_kernel(const float* __restrict__ x,
                                                      const __bf16* __restrict__ Acomp,
                                                      const float* __restrict__ bias,
                                                      const int* __restrict__ sel,
                                                      const int* __restrict__ unsel,
                                                      float* __restrict__ out) {
    // XCD-aware swizzle: xcd = id&7 (round-robin heuristic); each XCD owns 4 batches
    int id   = blockIdx.x;
    int xcd  = id & 7, slot = id >> 3;          // slot in [0,100)
    int bq   = slot / NTILE;                    // [0,4)
    int tile = slot - bq * NTILE;
    int b    = xcd * 4 + bq;
    int ptile = tile * TN;

    int t    = threadIdx.x;
    int lane = t & 63, wv = t >> 6;
    int fm   = lane & 15, fq = lane >> 4;
    int n_base = wv * 32;

    __shared__ __bf16 xlds[2][XROWS * LDX];

    const float*  x_b    = x + (size_t)b * IN_C * HW;
    const __bf16* a_base = Acomp + (size_t)b * (NGRP * 9 * 64 * 32);

    // per-s output pixel coords (fixed for whole kernel), s in [0,2)
    int pp[2], poh[2], pow_[2];
    #pragma unroll
    for (int s = 0; s < 2; ++s) {
        int p = ptile + n_base + s * 16 + fm;
        pp[s] = p;
        int pc = p < HW ? p : HW - 1;          // store-masked lanes clamp
        poh[s]  = pc / WIDTH;
        pow_[s] = pc - poh[s] * WIDTH;
    }

    // staging: thread t == px row (242 active), 32 ic loads per group
    int  sp   = t;
    bool sact = sp < XROWS;
    int  gp   = ptile - 57 + sp;
    gp = gp < 0 ? 0 : (gp > HW - 1 ? HW - 1 : gp);  // clamped; consumers mask invalids
    const float* sx = x_b + gp;

    // prologue: stage group 0 into buf 0
    if (sact) {
        #pragma unroll
        for (int oct = 0; oct < 4; ++oct) {
            float v[8];
            #pragma unroll
            for (int j = 0; j < 8; ++j) v[j] = sx[(size_t)(oct * 8 + j) * HW];
            bf16x8 o;
            #pragma unroll
            for (int j = 0; j < 8; ++j) o[j] = (__bf16)v[j];
            *(bf16x8*)&xlds[0][sp * LDX + oct * 8] = o;
        }
    }
    __syncthreads();

    f32x4 acc[4][2] = {};
    float pre[32];

    for (int g = 0; g < NGRP; ++g) {
        int cur = g & 1;
        // (a) issue next group's global loads (latency hidden under tap loop)
        if (g < NGRP - 1 && sact) {
            #pragma unroll
            for (int i = 0; i < 32; ++i)
                pre[i] = sx[(size_t)((g + 1) * 32 + i) * HW];
        }
        // (b) 9 taps from the staged slab
        const __bf16* gp_a = a_base + (size_t)g * 9 * 64 * 32;
        #pragma unroll
        for (int t9 = 0; t9 < 9; ++t9) {
            const int r = t9 / 3, c = t9 - 3 * (t9 / 3);
            const int shift = (r - 1) * WIDTH + (c - 1);
            const __bf16* ap = gp_a + (size_t)t9 * 64 * 32;
            bf16x8 af[4];
            #pragma unroll
            for (int mi = 0; mi < 4; ++mi)
                af[mi] = *(const bf16x8*)(ap + (size_t)(mi * 16 + fm) * 32 + fq * 8);
            #pragma unroll
            for (int s = 0; s < 2; ++s) {
                int ohr = poh[s] + r - 1, owc = pow_[s] + c - 1;
                bool ok = ((unsigned)ohr < 56u) && ((unsigned)owc < 56u);
                int n = n_base + s * 16 + fm;
                bf16x8 bfr = *(const bf16x8*)&xlds[cur][(n + 57 + shift) * LDX + fq * 8];
                bf16x8 z = {};
                bfr = ok ? bfr : z;
                #pragma unroll
                for (int mi = 0; mi < 4; ++mi)
                    acc[mi][s] = __builtin_amdgcn_mfma_f32_16x16x32_bf16(af[mi], bfr, acc[mi][s], 0, 0, 0);
            }
        }
        // (c) convert + write next slab to the other buffer, one barrier per group
        if (g < NGRP - 1) {
            if (sact) {
                #pragma unroll
                for (int oct = 0; oct < 4; ++oct) {
                    bf16x8 o;
                    #pragma unroll
                    for (int j = 0; j < 8; ++j) o[j] = (__bf16)pre[oct * 8 + j];
                    *(bf16x8*)&xlds[cur ^ 1][sp * LDX + oct * 8] = o;
                }
            }
            __syncthreads();
        }
    }

    // epilogue 1: bias + masked store of selected planes.
    // C/D: col(lane&15)=px, row=fq*4+reg=oc-slot
    const int* selb = sel + b * NF;
    size_t outb = (size_t)b * OUT_C * HW;
    #pragma unroll
    for (int mi = 0; mi < 4; ++mi) {
        #pragma unroll
        for (int reg = 0; reg < 4; ++reg) {
            int m  = mi * 16 + fq * 4 + reg;
            int oc = selb[m];
            float bs = bias[oc];
            float* orow = out + outb + (size_t)oc * HW;
            #pragma unroll
            for (int s = 0; s < 2; ++s)
                if (pp[s] < HW) orow[pp[s]] = acc[mi][s][reg] + bs;
        }
    }

    // epilogue 2: zero-fill unselected planes for this px tile (streaming, overlaps nothing hot)
    {
        const int* unselb = unsel + b * NU;
        int j = t & 31;                          // float4 index over 128 px
        bool jok = (ptile + j * 4) < HW;         // tail tile: only first 64 px exist
        float4 z = {0.f, 0.f, 0.f, 0.f};
        for (int u = t >> 5; u < NU; u += 8) {
            int oc = unselb[u];
            if (jok)
                *(float4*)(out + outb + (size_t)oc * HW + ptile + j * 4) = z;
        }
    }
}

extern "C" void kernel_launch(void* const* d_in, const int* in_sizes, int n_in,
                              void* d_out, int out_size, void* d_ws, size_t ws_size,
                              hipStream_t stream) {
    (void)in_sizes; (void)n_in; (void)ws_size; (void)out_size;
    const float* x        = (const float*)d_in[0];
    const float* weight   = (const float*)d_in[1];
    const float* bias     = (const float*)d_in[2];
    const float* router_w = (const float*)d_in[3];
    const float* router_b = (const float*)d_in[4];
    float* out = (float*)d_out;

    char* ws = (char*)d_ws;
    float*  pooled = (float*)ws;                       // 32 KB
    int*    sel    = (int*)(ws + 32768);               // 8 KB
    int*    unsel  = (int*)(ws + 40960);               // 56 KB
    __bf16* Acomp  = (__bf16*)(ws + 131072);           // 9.44 MB

    pool_kernel<<<NB * IN_C, 256, 0, stream>>>(x, pooled);
    router_kernel<<<NB, OUT_C, 0, stream>>>(pooled, router_w, router_b, sel, unsel);
    compact_w<<<NB * NGRP * 9, 256, 0, stream>>>(weight, sel, Acomp);

    conv_kernel<<<NTILE * NB, 256, 0, stream>>>(x, Acomp, bias, sel, unsel, out);
}

// Round 5
// 375.847 us; speedup vs baseline: 1.0810x; 1.0810x over previous
//
#include <hip/hip_runtime.h>

#define IN_C   256
#define OUT_C  512
#define WIDTH  56
#define HW     3136        // 56*56
#define KTOT   2304        // IN_C*9
#define NF     64
#define NU     448         // OUT_C - NF
#define NB     32
#define NGRP   8           // ic groups of 32
#define TN     64          // pixels per block (3136 = 49*64 exactly -> no tail)
#define NTILE  49
#define XROWS  178         // TN + 2*57 halo
#define LDX    40          // padded LDS row stride (bf16 elems) = 80 B, 16B-aligned

typedef __bf16 bf16x8 __attribute__((ext_vector_type(8)));
typedef float  f32x4  __attribute__((ext_vector_type(4)));

// ---------------- kernel 1: global average pool ----------------
__global__ __launch_bounds__(256) void pool_kernel(const float* __restrict__ x,
                                                   float* __restrict__ pooled) {
    int bc = blockIdx.x;
    const float4* src = (const float4*)(x + (size_t)bc * HW);
    float s = 0.f;
    for (int i = threadIdx.x; i < HW / 4; i += 256) {
        float4 v = src[i];
        s += v.x + v.y + v.z + v.w;
    }
    #pragma unroll
    for (int off = 32; off > 0; off >>= 1) s += __shfl_down(s, off, 64);
    __shared__ float wsum[4];
    int lane = threadIdx.x & 63, wv = threadIdx.x >> 6;
    if (lane == 0) wsum[wv] = s;
    __syncthreads();
    if (threadIdx.x == 0)
        pooled[bc] = (wsum[0] + wsum[1] + wsum[2] + wsum[3]) * (1.0f / HW);
}

// ---------------- kernel 2: router GEMV + top-64 selection ----------------
__global__ __launch_bounds__(512) void router_kernel(const float* __restrict__ pooled,
                                                     const float* __restrict__ rw,
                                                     const float* __restrict__ rb,
                                                     int* __restrict__ sel,
                                                     int* __restrict__ unsel) {
    int b = blockIdx.x;
    __shared__ float p[IN_C];
    __shared__ float v[OUT_C];
    __shared__ int   scount, ucount;
    int t = threadIdx.x;
    if (t < IN_C) p[t] = pooled[b * IN_C + t];
    if (t == 0) { scount = 0; ucount = 0; }
    __syncthreads();
    float acc = rb[t];
    const float* wrow = rw + (size_t)t * IN_C;
    for (int i = 0; i < IN_C; ++i) acc += p[i] * wrow[i];
    v[t] = acc;
    __syncthreads();
    // stable rank: count strictly-greater, plus equal-with-lower-index (matches top_k tie rule)
    int cnt = 0;
    for (int j = 0; j < OUT_C; ++j) {
        float o = v[j];
        cnt += (o > acc) || (o == acc && j < t);
    }
    if (cnt < NF) {
        int pos = atomicAdd(&scount, 1);   // order irrelevant: scatter by oc
        sel[b * NF + pos] = t;
    } else {
        int pos = atomicAdd(&ucount, 1);
        unsel[b * NU + pos] = t;
    }
}

// ---------------- kernel 3: weight compaction into MFMA-A fragment layout ----------------
// Acomp[((b*8+g)*9+tap)*64 + oc][32 icl] bf16. blockIdx = b*72 + g*9 + tap.
__global__ __launch_bounds__(256) void compact_w(const float* __restrict__ w,
                                                 const int* __restrict__ sel,
                                                 __bf16* __restrict__ Acomp) {
    int id = blockIdx.x;
    int b = id / 72, rem = id - b * 72;
    int g = rem / 9, tap = rem - g * 9;
    int t = threadIdx.x;
    int oc = t >> 2, q = t & 3;
    int s = sel[b * NF + oc];
    const float* wsrc = w + (size_t)s * KTOT + tap;   // + ic*9
    bf16x8 o;
    #pragma unroll
    for (int j = 0; j < 8; ++j)
        o[j] = (__bf16)wsrc[(g * 32 + q * 8 + j) * 9];
    *(bf16x8*)&Acomp[((size_t)id * 64 + oc) * 32 + q * 8] = o;
}

// ---------------- kernel 4: sparse conv — single-wave blocks, M64xN64, no barriers ----------------
// 1568 blocks (49 tiles x 32 batches, XCD-swizzled), 64 threads = 1 wave.
// Wave tile: M=64 selected ocs x N=64 px (16 acc frags). K: 8 ic-groups of 32.
// Per group: stage 178-row x 32-ic x-slab into single LDS buffer (in-wave DS ordering,
// no __syncthreads), then 9 taps read shifted rows. A-frags straight from Acomp (L2-hot).
// Zero-fill of unselected planes issued FIRST so the stores drain under the K-loop.
__global__ __launch_bounds__(64) void conv_kernel(const float* __restrict__ x,
                                                  const __bf16* __restrict__ Acomp,
                                                  const float* __restrict__ bias,
                                                  const int* __restrict__ sel,
                                                  const int* __restrict__ unsel,
                                                  float* __restrict__ out) {
    // XCD swizzle: all 49 tiles of a batch land on one XCD -> halo re-reads hit that L2
    int id   = blockIdx.x;
    int xcd  = id & 7, slot = id >> 3;          // slot in [0,196)
    int bq   = slot / NTILE;                    // [0,4)
    int tile = slot - bq * NTILE;
    int b    = xcd * 4 + bq;
    int ptile = tile * TN;

    int lane = threadIdx.x;                     // 0..63
    int fm   = lane & 15, fq = lane >> 4;

    __shared__ __bf16 xlds[XROWS * LDX];        // 14240 B -> up to 11 blocks/CU

    size_t outb = (size_t)b * OUT_C * HW;

    // ---- zero-fill unselected planes (nontemporal, drains under compute) ----
    {
        const int* unselb = unsel + b * NU;
        f32x4 z = {0.f, 0.f, 0.f, 0.f};
        for (int u = fq; u < NU; u += 4) {
            int oc = unselb[u];
            __builtin_nontemporal_store(z, (f32x4*)(out + outb + (size_t)oc * HW + ptile) + fm);
        }
    }

    const float*  x_b    = x + (size_t)b * IN_C * HW;
    const __bf16* a_base = Acomp + (size_t)b * (NGRP * 9 * 64 * 32);

    // output px coords per n-frag (all stores valid: 3136 = 49*64)
    int pp[4], poh[4], pow_[4];
    #pragma unroll
    for (int s = 0; s < 4; ++s) {
        int p = ptile + s * 16 + fm;
        pp[s]   = p;
        poh[s]  = p / WIDTH;
        pow_[s] = p - poh[s] * WIDTH;
    }

    // staging rows: it*64+lane, clamped px (consumers mask invalids via boundary test)
    int gp0[3]; bool act[3];
    #pragma unroll
    for (int it = 0; it < 3; ++it) {
        int sp = it * 64 + lane;
        act[it] = sp < XROWS;
        int gp = ptile - 57 + sp;
        gp = gp < 0 ? 0 : (gp > HW - 1 ? HW - 1 : gp);
        gp0[it] = gp;
    }

    f32x4 acc[4][4] = {};

    #pragma unroll 1
    for (int g = 0; g < NGRP; ++g) {
        // ---- stage group g slab: 178 rows x 32 ic (in-wave ordering, no barrier) ----
        #pragma unroll
        for (int it = 0; it < 3; ++it) {
            if (!act[it]) continue;
            int sp = it * 64 + lane;
            const float* sx = x_b + (size_t)(g * 32) * HW + gp0[it];
            #pragma unroll
            for (int oct = 0; oct < 4; ++oct) {
                float v[8];
                #pragma unroll
                for (int j = 0; j < 8; ++j) v[j] = sx[(size_t)(oct * 8 + j) * HW];
                bf16x8 o;
                #pragma unroll
                for (int j = 0; j < 8; ++j) o[j] = (__bf16)v[j];
                *(bf16x8*)&xlds[sp * LDX + oct * 8] = o;
            }
        }
        // ---- 9 taps ----
        const __bf16* gp_a = a_base + (size_t)g * 9 * 64 * 32;
        #pragma unroll
        for (int t9 = 0; t9 < 9; ++t9) {
            const int r = t9 / 3, c = t9 - 3 * (t9 / 3);
            const int shift = (r - 1) * WIDTH + (c - 1);
            const __bf16* ap = gp_a + (size_t)t9 * 64 * 32;
            bf16x8 af[4];
            #pragma unroll
            for (int mi = 0; mi < 4; ++mi)
                af[mi] = *(const bf16x8*)(ap + (size_t)(mi * 16 + fm) * 32 + fq * 8);
            #pragma unroll
            for (int s = 0; s < 4; ++s) {
                int ohr = poh[s] + r - 1, owc = pow_[s] + c - 1;
                bool ok = ((unsigned)ohr < 56u) && ((unsigned)owc < 56u);
                bf16x8 bfr = *(const bf16x8*)&xlds[(s * 16 + fm + 57 + shift) * LDX + fq * 8];
                bf16x8 zz = {};
                bfr = ok ? bfr : zz;
                #pragma unroll
                for (int mi = 0; mi < 4; ++mi)
                    acc[mi][s] = __builtin_amdgcn_mfma_f32_16x16x32_bf16(af[mi], bfr, acc[mi][s], 0, 0, 0);
            }
        }
    }

    // ---- selected planes: bias + nontemporal store. C/D: col(lane&15)=px, row=fq*4+reg ----
    const int* selb = sel + b * NF;
    #pragma unroll
    for (int mi = 0; mi < 4; ++mi) {
        #pragma unroll
        for (int reg = 0; reg < 4; ++reg) {
            int oc = selb[mi * 16 + fq * 4 + reg];
            float bs = bias[oc];
            float* orow = out + outb + (size_t)oc * HW;
            #pragma unroll
            for (int s = 0; s < 4; ++s)
                __builtin_nontemporal_store(acc[mi][s][reg] + bs, &orow[pp[s]]);
        }
    }
}

extern "C" void kernel_launch(void* const* d_in, const int* in_sizes, int n_in,
                              void* d_out, int out_size, void* d_ws, size_t ws_size,
                              hipStream_t stream) {
    (void)in_sizes; (void)n_in; (void)ws_size; (void)out_size;
    const float* x        = (const float*)d_in[0];
    const float* weight   = (const float*)d_in[1];
    const float* bias     = (const float*)d_in[2];
    const float* router_w = (const float*)d_in[3];
    const float* router_b = (const float*)d_in[4];
    float* out = (float*)d_out;

    char* ws = (char*)d_ws;
    float*  pooled = (float*)ws;                       // 32 KB
    int*    sel    = (int*)(ws + 32768);               // 8 KB
    int*    unsel  = (int*)(ws + 40960);               // 56 KB
    __bf16* Acomp  = (__bf16*)(ws + 131072);           // 9.44 MB

    pool_kernel<<<NB * IN_C, 256, 0, stream>>>(x, pooled);
    router_kernel<<<NB, OUT_C, 0, stream>>>(pooled, router_w, router_b, sel, unsel);
    compact_w<<<NB * NGRP * 9, 256, 0, stream>>>(weight, sel, Acomp);

    conv_kernel<<<NTILE * NB, 64, 0, stream>>>(x, Acomp, bias, sel, unsel, out);
}